// Round 3
// baseline (89.258 us; speedup 1.0000x reference)
//
#include <hip/hip_runtime.h>
#include <hip/hip_bf16.h>
#include <stdint.h>

#define NB    32
#define CIN   128
#define HIN   56
#define HW    (HIN*HIN)     // 3136
#define OCH   256
#define OHW   54
#define SPB   (OHW*OHW)     // 2916 spatial outputs per batch
#define KSZ   (CIN*9)       // 1152 = GEMM K
#define BM    128           // oc rows per block
#define BN    256           // flattened (n,sp) cols per block
#define BK    64
#define NKS   (KSZ/BK)      // 18 K-steps
#define TOTC  (NB*SPB)      // 93312 total columns
#define NT    365           // ceil(93312/256)

typedef __attribute__((ext_vector_type(8))) short bf16x8;
typedef __attribute__((ext_vector_type(4))) float f32x4;

typedef __attribute__((address_space(1))) const uint32_t g_u32;
typedef __attribute__((address_space(3))) uint32_t l_u32;
static __device__ __forceinline__ void gl_lds16(const void* g, void* l) {
    __builtin_amdgcn_global_load_lds((g_u32*)g, (l_u32*)l, 16, 0, 0);
}

// ---- pre-pass 1: x NCHW f32 -> NHWC bf16 (LDS tiled transpose) ----
__global__ void xpose_cast(const float* __restrict__ x, __hip_bfloat16* __restrict__ xt) {
    __shared__ float tile[32][33];       // [c][hw]
    const int hw0 = blockIdx.x * 32;
    const int c0  = blockIdx.y * 32;
    const int n   = blockIdx.z;
    const int tx = threadIdx.x, ty = threadIdx.y;
    const float* xp = x + ((size_t)n*CIN + c0)*HW + hw0;
    #pragma unroll
    for (int i = ty; i < 32; i += 8)
        tile[i][tx] = xp[(size_t)i*HW + tx];
    __syncthreads();
    const int t = ty*32 + tx;
    const int hwl = t >> 3, q = t & 7;
    ushort4 v;
    v.x = __bfloat16_as_ushort(__float2bfloat16(tile[q*4+0][hwl]));
    v.y = __bfloat16_as_ushort(__float2bfloat16(tile[q*4+1][hwl]));
    v.z = __bfloat16_as_ushort(__float2bfloat16(tile[q*4+2][hwl]));
    v.w = __bfloat16_as_ushort(__float2bfloat16(tile[q*4+3][hwl]));
    __hip_bfloat16* op = xt + ((size_t)n*HW + hw0 + hwl)*CIN + c0 + q*4;
    *(ushort4*)op = v;
}

// ---- pre-pass 2: weight OIHW f32 -> [oc][(kh*3+kw)*128+ic] bf16 ----
__global__ void wcast(const float* __restrict__ w, __hip_bfloat16* __restrict__ wt) {
    int tid = blockIdx.x*256 + threadIdx.x;
    if (tid >= OCH*KSZ) return;
    int oc = tid / KSZ, r = tid % KSZ;
    int pos = r >> 7, ic = r & 127;
    wt[tid] = __float2bfloat16(w[((size_t)(oc*CIN + ic))*9 + pos]);
}

// ---- main: implicit-GEMM bf16 MFMA conv, counted-vmcnt triple-buffer pipeline ----
// grid (365, 2), block 512 (8 waves = 2M x 4N of 64x64)
__global__ __launch_bounds__(512, 2)
void conv_mfma(const __hip_bfloat16* __restrict__ xt,
               const __hip_bfloat16* __restrict__ wt,
               const float* __restrict__ bias,
               float* __restrict__ out) {
    // 3 buffers x (A 128x64 + B 256x64 bf16) = 3 x 48KB = 144KB
    // granule-XOR swizzle: linear gl_lds dest + inverse-swizzled SOURCE + swizzled read
    __shared__ uint4 smem[3*3072];

    const int t = threadIdx.x;
    const int tile = blockIdx.x, octile = blockIdx.y;
    const int lane = t & 63, wid = t >> 6;
    const int wm = wid >> 2, wn = wid & 3;     // 2M x 4N waves
    const int lr = lane & 15, lq = lane >> 4;

    // --- staging sources (A: 2 issues x 512 thr, B: 4 issues x 512 thr)
    const __hip_bfloat16* asrc[2];
    #pragma unroll
    for (int i = 0; i < 2; ++i) {
        int p = i*512 + t;
        int row = p >> 3, g = (p & 7) ^ (row & 7);
        asrc[i] = wt + (size_t)(octile*BM + row)*KSZ + g*8;
    }
    const __hip_bfloat16* bsrc[4];
    #pragma unroll
    for (int i = 0; i < 4; ++i) {
        int p = i*512 + t;
        int row = p >> 3, g = (p & 7) ^ (row & 7);
        int colg = tile*BN + row; if (colg >= TOTC) colg = TOTC - 1;  // clamp pad cols
        int n = colg / SPB, rem = colg - n*SPB;
        int oh = rem / OHW, ow = rem - oh*OHW;
        bsrc[i] = xt + ((size_t)(n*HIN + oh)*HIN + ow)*CIN + g*8;
    }

    // part 0: A0,A1,B0 ; part 1: B1,B2,B3  (3 gl_lds each, 6 per K-step)
    auto issue = [&](int ks, int part) {
        uint4* Ab = smem + (ks % 3)*3072;
        uint4* Bb = Ab + 1024;
        const int pos = ks >> 1;
        const int kh = pos / 3, kw = pos - kh*3;
        const int aoff = ks*BK;
        const int boff = (kh*HIN + kw)*CIN + (ks & 1)*64;
        if (part == 0) {
            gl_lds16(asrc[0] + aoff, Ab + t);
            gl_lds16(asrc[1] + aoff, Ab + 512 + t);
            gl_lds16(bsrc[0] + boff, Bb + t);
        } else {
            gl_lds16(bsrc[1] + boff, Bb + 512 + t);
            gl_lds16(bsrc[2] + boff, Bb + 1024 + t);
            gl_lds16(bsrc[3] + boff, Bb + 1536 + t);
        }
    };

    f32x4 acc[4][4];
    #pragma unroll
    for (int i = 0; i < 4; ++i)
        #pragma unroll
        for (int j = 0; j < 4; ++j)
            acc[i][j] = (f32x4){0.f, 0.f, 0.f, 0.f};

    // prologue: tiles 0 and 1 in flight (12 loads/wave outstanding)
    issue(0, 0); issue(0, 1);
    issue(1, 0); issue(1, 1);

    for (int ks = 0; ks < NKS; ++ks) {
        // own oldest-6 (= tile ks) retired; newer 6 (tile ks+1) stay in flight
        if (ks < NKS-1) asm volatile("s_waitcnt vmcnt(6)" ::: "memory");
        else            asm volatile("s_waitcnt vmcnt(0)" ::: "memory");
        __builtin_amdgcn_s_barrier();          // all waves: tile ks landed; ks-1 reads done
        __builtin_amdgcn_sched_barrier(0);

        const uint4* Ab = smem + (ks % 3)*3072;
        const uint4* Bb = Ab + 1024;

        #pragma unroll
        for (int kk = 0; kk < 2; ++kk) {
            if (ks + 2 < NKS) issue(ks + 2, kk);   // overwrite buf[(ks-1)%3] — reads done pre-barrier
            bf16x8 a[4], b[4];
            #pragma unroll
            for (int mi = 0; mi < 4; ++mi) {
                int ra = wm*64 + mi*16 + lr;
                a[mi] = *(bf16x8*)&Ab[ra*8 + ((kk*4 + lq) ^ (ra & 7))];
            }
            #pragma unroll
            for (int ni = 0; ni < 4; ++ni) {
                int rb = wn*64 + ni*16 + lr;
                b[ni] = *(bf16x8*)&Bb[rb*8 + ((kk*4 + lq) ^ (rb & 7))];
            }
            __builtin_amdgcn_s_setprio(1);
            #pragma unroll
            for (int mi = 0; mi < 4; ++mi)
                #pragma unroll
                for (int ni = 0; ni < 4; ++ni)
                    acc[mi][ni] = __builtin_amdgcn_mfma_f32_16x16x32_bf16(
                        a[mi], b[ni], acc[mi][ni], 0, 0, 0);
            __builtin_amdgcn_s_setprio(0);
        }
    }

    __syncthreads();    // all tile-17 reads done before smem is reused for epilogue

    // --- epilogue: restage via LDS, coalesced float4 stores ---
    float (*eps)[264] = (float (*)[264])smem;   // [64][264] = 67.6KB
    for (int h = 0; h < 2; ++h) {
        if (wm == h) {
            #pragma unroll
            for (int mi = 0; mi < 4; ++mi) {
                int rl = mi*16 + lq*4;
                #pragma unroll
                for (int ni = 0; ni < 4; ++ni) {
                    int cl = wn*64 + ni*16 + lr;
                    #pragma unroll
                    for (int r = 0; r < 4; ++r)
                        eps[rl + r][cl] = acc[mi][ni][r];
                }
            }
        }
        __syncthreads();
        const int cl4 = (t & 63) * 4;            // 0..252
        const int rsub = t >> 6;                 // 0..7
        const int colg = tile*BN + cl4;
        if (colg < TOTC) {                       // 4-col group never straddles a batch
            const int n = colg / SPB;
            const int sp = colg - n*SPB;
            #pragma unroll
            for (int pass = 0; pass < 8; ++pass) {
                int rl = pass*8 + rsub;
                int rg = octile*BM + h*64 + rl;
                f32x4 v = *(f32x4*)&eps[rl][cl4];
                v = v + bias[rg];
                *(f32x4*)&out[((size_t)n*OCH + rg)*SPB + sp] = v;
            }
        }
        __syncthreads();
    }
}

// ---- fallback (only if ws too small): direct fp32 conv ----
__global__ void conv_naive(const float* __restrict__ x, const float* __restrict__ w,
                           const float* __restrict__ bias, float* __restrict__ out) {
    size_t tid = (size_t)blockIdx.x*256 + threadIdx.x;
    const size_t total = (size_t)NB*OCH*SPB;
    if (tid >= total) return;
    int col = (int)(tid % SPB);
    int oc  = (int)((tid / SPB) % OCH);
    int n   = (int)(tid / ((size_t)SPB*OCH));
    int oh = col / OHW, ow = col % OHW;
    float s = bias[oc];
    for (int ic = 0; ic < CIN; ++ic)
        #pragma unroll
        for (int kh = 0; kh < 3; ++kh)
            #pragma unroll
            for (int kw = 0; kw < 3; ++kw)
                s += x[((size_t)(n*CIN+ic)*HIN + oh+kh)*HIN + ow+kw]
                   * w[((size_t)(oc*CIN+ic)*3 + kh)*3 + kw];
    out[tid] = s;
}

extern "C" void kernel_launch(void* const* d_in, const int* in_sizes, int n_in,
                              void* d_out, int out_size, void* d_ws, size_t ws_size,
                              hipStream_t stream) {
    const float* x    = (const float*)d_in[0];
    const float* w    = (const float*)d_in[1];
    const float* bias = (const float*)d_in[2];
    float* out = (float*)d_out;

    const size_t xt_bytes = (size_t)NB*HW*CIN*sizeof(__hip_bfloat16);   // 25,690,112
    const size_t wt_bytes = (size_t)OCH*KSZ*sizeof(__hip_bfloat16);     //    589,824

    if (ws_size >= xt_bytes + wt_bytes) {
        __hip_bfloat16* xt  = (__hip_bfloat16*)d_ws;
        __hip_bfloat16* wtp = (__hip_bfloat16*)((char*)d_ws + xt_bytes);
        hipLaunchKernelGGL(xpose_cast, dim3(HW/32, CIN/32, NB), dim3(32, 8), 0, stream, x, xt);
        hipLaunchKernelGGL(wcast, dim3((OCH*KSZ + 255)/256), dim3(256), 0, stream, w, wtp);
        hipLaunchKernelGGL(conv_mfma, dim3(NT, OCH/BM), dim3(512), 0, stream,
                           xt, wtp, bias, out);
    } else {
        size_t total = (size_t)NB*OCH*SPB;
        hipLaunchKernelGGL(conv_naive, dim3((unsigned)((total + 255)/256)), dim3(256), 0, stream,
                           x, w, bias, out);
    }
}